// Round 3
// baseline (3214.210 us; speedup 1.0000x reference)
//
#include <hip/hip_runtime.h>
#include <hip/hip_bf16.h>

typedef unsigned short u16;
typedef __bf16 bf16x8 __attribute__((ext_vector_type(8)));
typedef float f32x4 __attribute__((ext_vector_type(4)));

__device__ __forceinline__ float bf2f(u16 v) { return __uint_as_float(((unsigned)v) << 16); }
__device__ __forceinline__ u16 f2bf(float f) {
  unsigned u = __float_as_uint(f);
  u += 0x7FFFu + ((u >> 16) & 1u);
  return (u16)(u >> 16);
}
__device__ __forceinline__ float gelu_exact(float x) {
  return 0.5f * x * (1.0f + erff(x * 0.70710678118654752f));
}

// ---------------- dtype sniffer ----------------
// bf16 N(0,1) data: even-indexed u16s decode to |v| in [2^-8,16] w.p. ~99.7%.
// fp32 N(0,1) data: even-indexed u16s are uniform mantissa halves (~5% in range).
__global__ void sniff_kernel(const u16* __restrict__ x, int* __restrict__ flag) {
  int tid = threadIdx.x;  // 64
  int hits = 0;
  #pragma unroll
  for (int s = 0; s < 2; ++s) {
    float f = fabsf(bf2f(x[2 * (tid + 64 * s)]));
    hits += (f >= 0.00390625f && f <= 16.0f) ? 1 : 0;
  }
  #pragma unroll
  for (int off = 32; off; off >>= 1) hits += __shfl_xor(hits, off);
  if (tid == 0) flag[0] = (hits >= 64) ? 1 : 0;  // 1 = bf16, 0 = fp32
}

// ---------------- input -> bf16 copy/convert ----------------
__global__ __launch_bounds__(256) void in2bf_kernel(const void* __restrict__ src, u16* __restrict__ dst,
                                                    int n4, const int* __restrict__ flagp) {
  int i = blockIdx.x * 256 + threadIdx.x;
  if (i >= n4) return;
  if (*flagp) {
    ((ushort4*)dst)[i] = ((const ushort4*)src)[i];
  } else {
    float4 v = ((const float4*)src)[i];
    ushort4 o; o.x = f2bf(v.x); o.y = f2bf(v.y); o.z = f2bf(v.z); o.w = f2bf(v.w);
    ((ushort4*)dst)[i] = o;
  }
}

// ---------------- input -> fp32 copy/convert (residual stream init) ----------------
__global__ __launch_bounds__(256) void in2f32_kernel(const void* __restrict__ src, float* __restrict__ dst,
                                                     int n4, const int* __restrict__ flagp) {
  int i = blockIdx.x * 256 + threadIdx.x;
  if (i >= n4) return;
  if (*flagp) {
    ushort4 v = ((const ushort4*)src)[i];
    float4 o; o.x = bf2f(v.x); o.y = bf2f(v.y); o.z = bf2f(v.z); o.w = bf2f(v.w);
    ((float4*)dst)[i] = o;
  } else {
    ((float4*)dst)[i] = ((const float4*)src)[i];
  }
}

// ---------------- weight transpose: in [R,C] -> out [C,R] bf16, dual-dtype read ----------------
__global__ __launch_bounds__(256) void transpose_k(const void* __restrict__ in_, u16* __restrict__ out,
                                                   int R, int C, const int* __restrict__ flagp) {
  int flag = *flagp;
  __shared__ u16 tile[32][33];
  int c0 = blockIdx.x * 32, r0 = blockIdx.y * 32;
  int tx = threadIdx.x & 31, ty = threadIdx.x >> 5;
  #pragma unroll
  for (int j = 0; j < 32; j += 8) {
    size_t idx = (size_t)(r0 + ty + j) * C + c0 + tx;
    tile[ty + j][tx] = flag ? ((const u16*)in_)[idx] : f2bf(((const float*)in_)[idx]);
  }
  __syncthreads();
  #pragma unroll
  for (int j = 0; j < 32; j += 8)
    out[(size_t)(c0 + ty + j) * R + r0 + tx] = tile[tx][ty + j];
}

// ---------------- LayerNorm: fp32 in -> bf16 out, D=1024, one block per row ----------------
// w,b are internal bf16 (pre-converted pool)
__global__ __launch_bounds__(256) void ln_kernel(const float* __restrict__ x,
                                                 const u16* __restrict__ w, const u16* __restrict__ b,
                                                 u16* __restrict__ out) {
  int row = blockIdx.x, tid = threadIdx.x;
  float4 v = ((const float4*)(x + (size_t)row * 1024))[tid];
  float s = v.x + v.y + v.z + v.w;
  #pragma unroll
  for (int off = 32; off; off >>= 1) s += __shfl_xor(s, off);
  __shared__ float red1[4], red2[4];
  if ((tid & 63) == 0) red1[tid >> 6] = s;
  __syncthreads();
  float mean = (red1[0] + red1[1] + red1[2] + red1[3]) * (1.0f / 1024.0f);
  float d0 = v.x - mean, d1 = v.y - mean, d2 = v.z - mean, d3 = v.w - mean;
  float vs = d0 * d0 + d1 * d1 + d2 * d2 + d3 * d3;
  #pragma unroll
  for (int off = 32; off; off >>= 1) vs += __shfl_xor(vs, off);
  if ((tid & 63) == 0) red2[tid >> 6] = vs;
  __syncthreads();
  float var = (red2[0] + red2[1] + red2[2] + red2[3]) * (1.0f / 1024.0f);
  float rs = rsqrtf(var + 1e-5f);
  int c = tid * 4;
  ushort4 o;
  o.x = f2bf(d0 * rs * bf2f(w[c + 0]) + bf2f(b[c + 0]));
  o.y = f2bf(d1 * rs * bf2f(w[c + 1]) + bf2f(b[c + 1]));
  o.z = f2bf(d2 * rs * bf2f(w[c + 2]) + bf2f(b[c + 2]));
  o.w = f2bf(d3 * rs * bf2f(w[c + 3]) + bf2f(b[c + 3]));
  ((ushort4*)(out + (size_t)row * 1024))[tid] = o;
}

// ---------------- TN GEMM: C[M,N] = A[M,K] @ Bt[N,K]^T + bias, bf16 MFMA ----------------
// MODE 0: out = bf16(r)
// MODE 1: resid_out = resid_in + r   (fp32 accumulate)
// MODE 2: out = bf16(gelu(r))
// MODE 3: out = resid_in + r, stored per *flagp (bf16 or fp32) -> d_out
#define LDK 72  // 64 + 8 pad (16B) -> 2-way LDS conflicts only (free)

template <int MODE>
__global__ __launch_bounds__(256) void gemm_tn(const u16* __restrict__ A, const u16* __restrict__ Bt,
                                               const u16* __restrict__ bias,
                                               const float* __restrict__ resid_in, float* __restrict__ resid_out,
                                               void* __restrict__ outp, int M, int N, int K,
                                               const int* __restrict__ flagp) {
  __shared__ __align__(16) u16 As[128 * LDK];
  __shared__ __align__(16) u16 Bs[128 * LDK];
  int n0 = blockIdx.x * 128, m0 = blockIdx.y * 128;
  int tid = threadIdx.x;
  int lane = tid & 63, w = tid >> 6;
  int wm = w & 1, wn = w >> 1;
  int flag = (MODE == 3) ? *flagp : 0;
  f32x4 acc[4][4];
  #pragma unroll
  for (int i = 0; i < 4; i++)
    #pragma unroll
    for (int j = 0; j < 4; j++) acc[i][j] = (f32x4){0.f, 0.f, 0.f, 0.f};

  int trow = tid >> 3, tcol = tid & 7;
  for (int k0 = 0; k0 < K; k0 += 64) {
    #pragma unroll
    for (int r = 0; r < 4; ++r) {
      int row = trow + 32 * r;
      *(uint4*)&As[row * LDK + tcol * 8] = *(const uint4*)&A[(size_t)(m0 + row) * K + k0 + tcol * 8];
      *(uint4*)&Bs[row * LDK + tcol * 8] = *(const uint4*)&Bt[(size_t)(n0 + row) * K + k0 + tcol * 8];
    }
    __syncthreads();
    #pragma unroll
    for (int kk = 0; kk < 64; kk += 32) {
      int kidx = kk + (lane >> 4) * 8;
      bf16x8 af[4], bfr[4];
      #pragma unroll
      for (int i = 0; i < 4; i++) {
        af[i]  = *(const bf16x8*)&As[(wm * 64 + i * 16 + (lane & 15)) * LDK + kidx];
        bfr[i] = *(const bf16x8*)&Bs[(wn * 64 + i * 16 + (lane & 15)) * LDK + kidx];
      }
      #pragma unroll
      for (int mi = 0; mi < 4; mi++)
        #pragma unroll
        for (int ni = 0; ni < 4; ni++)
          acc[mi][ni] = __builtin_amdgcn_mfma_f32_16x16x32_bf16(af[mi], bfr[ni], acc[mi][ni], 0, 0, 0);
    }
    __syncthreads();
  }
  // epilogue: C/D layout col = lane&15, row = (lane>>4)*4 + r
  int col_base = n0 + wn * 64, row_base = m0 + wm * 64;
  #pragma unroll
  for (int mi = 0; mi < 4; mi++) {
    #pragma unroll
    for (int ni = 0; ni < 4; ni++) {
      int col = col_base + ni * 16 + (lane & 15);
      float bv = bf2f(bias[col]);
      #pragma unroll
      for (int r = 0; r < 4; r++) {
        int row = row_base + mi * 16 + (lane >> 4) * 4 + r;
        float vv = acc[mi][ni][r] + bv;
        size_t idx = (size_t)row * N + col;
        if (MODE == 0) ((u16*)outp)[idx] = f2bf(vv);
        else if (MODE == 1) resid_out[idx] = resid_in[idx] + vv;
        else if (MODE == 2) ((u16*)outp)[idx] = f2bf(gelu_exact(vv));
        else {
          float ov = resid_in[idx] + vv;
          if (flag) ((u16*)outp)[idx] = f2bf(ov);
          else ((float*)outp)[idx] = ov;
        }
      }
    }
  }
}

// ---------------- Flash-style attention (VALU), HD=64 ----------------
__global__ __launch_bounds__(256) void attn_kernel(const u16* __restrict__ Q, const u16* __restrict__ K,
                                                   const u16* __restrict__ V, u16* __restrict__ O,
                                                   int T, int S, int qstride, int kstride, int causal) {
  int bh = blockIdx.y, b = bh >> 4, h = bh & 15;
  const u16* Qb = Q + (size_t)b * T * qstride + h * 64;
  const u16* Kb = K + (size_t)b * S * kstride + h * 64;
  const u16* Vb = V + (size_t)b * S * kstride + h * 64;
  u16* Ob = O + (size_t)b * T * 1024 + h * 64;

  int tid = threadIdx.x, lane = tid & 63, w = tid >> 6;
  int qt = blockIdx.x * 64;

  __shared__ float Qs[64][65];
  __shared__ float Ks[64][65];
  __shared__ float Vs[64][65];

  #pragma unroll
  for (int i = 0; i < 16; ++i) {
    int el = tid + 256 * i;
    int r = el >> 6, d = el & 63;
    Qs[r][d] = bf2f(Qb[(size_t)(qt + r) * qstride + d]);
  }

  float m_i[16], l_i[16], o_i[16];
  #pragma unroll
  for (int i = 0; i < 16; i++) { m_i[i] = -1e30f; l_i[i] = 0.f; o_i[i] = 0.f; }

  int nk = causal ? (blockIdx.x + 1) * 64 : S;
  const float scale = 0.125f;  // 1/sqrt(64)

  for (int s0 = 0; s0 < nk; s0 += 64) {
    __syncthreads();
    #pragma unroll
    for (int i = 0; i < 16; ++i) {
      int el = tid + 256 * i;
      int r = el >> 6, d = el & 63;
      Ks[r][d] = bf2f(Kb[(size_t)(s0 + r) * kstride + d]);
      Vs[r][d] = bf2f(Vb[(size_t)(s0 + r) * kstride + d]);
    }
    __syncthreads();
    #pragma unroll
    for (int i = 0; i < 16; ++i) {
      int row = w * 16 + i;
      int t_glob = qt + row;
      float sc = 0.f;
      #pragma unroll 16
      for (int d = 0; d < 64; ++d) sc += Qs[row][d] * Ks[lane][d];
      sc *= scale;
      if (causal && (s0 + lane > t_glob)) sc = -1e30f;
      float mx = sc;
      #pragma unroll
      for (int off = 32; off; off >>= 1) mx = fmaxf(mx, __shfl_xor(mx, off));
      float mnew = fmaxf(m_i[i], mx);
      float p = __expf(sc - mnew);
      float ps = p;
      #pragma unroll
      for (int off = 32; off; off >>= 1) ps += __shfl_xor(ps, off);
      float alpha = __expf(m_i[i] - mnew);
      l_i[i] = l_i[i] * alpha + ps;
      m_i[i] = mnew;
      float acc = 0.f;
      #pragma unroll 8
      for (int s = 0; s < 64; ++s) {
        float pv = __shfl(p, s);
        acc += pv * Vs[s][lane];
      }
      o_i[i] = o_i[i] * alpha + acc;
    }
  }
  #pragma unroll
  for (int i = 0; i < 16; ++i) {
    int t_glob = qt + w * 16 + i;
    Ob[(size_t)t_glob * 1024 + lane] = f2bf(o_i[i] / l_i[i]);
  }
}

extern "C" void kernel_launch(void* const* d_in, const int* in_sizes, int n_in,
                              void* d_out, int out_size, void* d_ws, size_t ws_size,
                              hipStream_t stream) {
  const void* x_in   = d_in[0];
  const void* enc_in = d_in[1];
  const void* ln1_w = d_in[4];  const void* ln1_b = d_in[5];
  const void* qkv_w = d_in[6];  const void* qkv_b = d_in[7];
  const void* proj_w = d_in[8]; const void* proj_b = d_in[9];
  const void* ln2_w = d_in[10]; const void* ln2_b = d_in[11];
  const void* q_w = d_in[12];   const void* q_b = d_in[13];
  const void* k_w = d_in[14];   const void* k_b = d_in[15];
  const void* v_w = d_in[16];   const void* v_b = d_in[17];
  const void* out_w = d_in[18]; const void* out_b = d_in[19];
  const void* ln3_w = d_in[20]; const void* ln3_b = d_in[21];
  const void* mlp1_w = d_in[22]; const void* mlp1_b = d_in[23];
  const void* mlp2_w = d_in[24]; const void* mlp2_b = d_in[25];

  // ---- workspace layout (~71 MB) ----
  char* ws = (char*)d_ws;
  size_t off = 0;
  auto alloc = [&](size_t bytes) { char* p = ws + off; off += (bytes + 255) & ~(size_t)255; return p; };
  float* xf   = (float*)alloc(4096ull * 1024 * 4);
  u16* hb     = (u16*)alloc(4096ull * 1024 * 2);
  u16* big    = (u16*)alloc(4096ull * 4096 * 2);
  u16* wT     = (u16*)alloc(3072ull * 1024 * 2);
  u16* encb   = (u16*)alloc(2304ull * 768 * 2);
  u16* pool   = (u16*)alloc(20480ull * 2);
  int* flag   = (int*)alloc(256);
  (void)ws_size;

  u16* q_bf = big;
  u16* k_bf = big + 4096ull * 1024;
  u16* v_bf = big + (4096ull + 2304) * 1024;

  // bf16 parameter pool offsets
  u16 *p_ln1w = pool, *p_ln1b = pool + 1024, *p_ln2w = pool + 2048, *p_ln2b = pool + 3072;
  u16 *p_ln3w = pool + 4096, *p_ln3b = pool + 5120;
  u16 *p_qkvb = pool + 6144, *p_projb = pool + 9216, *p_qb = pool + 10240, *p_kb = pool + 11264;
  u16 *p_vb = pool + 12288, *p_outb = pool + 13312, *p_m1b = pool + 14336, *p_m2b = pool + 18432;

  // ---- dtype sniff + input conversion ----
  sniff_kernel<<<1, 64, 0, stream>>>((const u16*)x_in, flag);
  in2f32_kernel<<<4096, 256, 0, stream>>>(x_in, xf, 1048576, flag);
  in2bf_kernel<<<1728, 256, 0, stream>>>(enc_in, encb, 442368, flag);
  in2bf_kernel<<<1, 256, 0, stream>>>(ln1_w, p_ln1w, 256, flag);
  in2bf_kernel<<<1, 256, 0, stream>>>(ln1_b, p_ln1b, 256, flag);
  in2bf_kernel<<<1, 256, 0, stream>>>(ln2_w, p_ln2w, 256, flag);
  in2bf_kernel<<<1, 256, 0, stream>>>(ln2_b, p_ln2b, 256, flag);
  in2bf_kernel<<<1, 256, 0, stream>>>(ln3_w, p_ln3w, 256, flag);
  in2bf_kernel<<<1, 256, 0, stream>>>(ln3_b, p_ln3b, 256, flag);
  in2bf_kernel<<<3, 256, 0, stream>>>(qkv_b, p_qkvb, 768, flag);
  in2bf_kernel<<<1, 256, 0, stream>>>(proj_b, p_projb, 256, flag);
  in2bf_kernel<<<1, 256, 0, stream>>>(q_b, p_qb, 256, flag);
  in2bf_kernel<<<1, 256, 0, stream>>>(k_b, p_kb, 256, flag);
  in2bf_kernel<<<1, 256, 0, stream>>>(v_b, p_vb, 256, flag);
  in2bf_kernel<<<1, 256, 0, stream>>>(out_b, p_outb, 256, flag);
  in2bf_kernel<<<4, 256, 0, stream>>>(mlp1_b, p_m1b, 1024, flag);
  in2bf_kernel<<<1, 256, 0, stream>>>(mlp2_b, p_m2b, 256, flag);

  // ---- self-attention block ----
  ln_kernel<<<4096, 256, 0, stream>>>(xf, p_ln1w, p_ln1b, hb);
  transpose_k<<<dim3(96, 32), 256, 0, stream>>>(qkv_w, wT, 1024, 3072, flag);
  gemm_tn<0><<<dim3(24, 32), 256, 0, stream>>>(hb, wT, p_qkvb, nullptr, nullptr, big, 4096, 3072, 1024, flag);
  attn_kernel<<<dim3(16, 64), 256, 0, stream>>>(big, big + 1024, big + 2048, hb, 1024, 1024, 3072, 3072, 1);
  transpose_k<<<dim3(32, 32), 256, 0, stream>>>(proj_w, wT, 1024, 1024, flag);
  gemm_tn<1><<<dim3(8, 32), 256, 0, stream>>>(hb, wT, p_projb, xf, xf, nullptr, 4096, 1024, 1024, flag);

  // ---- cross-attention block ----
  ln_kernel<<<4096, 256, 0, stream>>>(xf, p_ln2w, p_ln2b, hb);
  transpose_k<<<dim3(32, 32), 256, 0, stream>>>(q_w, wT, 1024, 1024, flag);
  gemm_tn<0><<<dim3(8, 32), 256, 0, stream>>>(hb, wT, p_qb, nullptr, nullptr, q_bf, 4096, 1024, 1024, flag);
  transpose_k<<<dim3(32, 24), 256, 0, stream>>>(k_w, wT, 768, 1024, flag);
  gemm_tn<0><<<dim3(8, 18), 256, 0, stream>>>(encb, wT, p_kb, nullptr, nullptr, k_bf, 2304, 1024, 768, flag);
  transpose_k<<<dim3(32, 24), 256, 0, stream>>>(v_w, wT, 768, 1024, flag);
  gemm_tn<0><<<dim3(8, 18), 256, 0, stream>>>(encb, wT, p_vb, nullptr, nullptr, v_bf, 2304, 1024, 768, flag);
  attn_kernel<<<dim3(16, 64), 256, 0, stream>>>(q_bf, k_bf, v_bf, hb, 1024, 576, 1024, 1024, 0);
  transpose_k<<<dim3(32, 32), 256, 0, stream>>>(out_w, wT, 1024, 1024, flag);
  gemm_tn<1><<<dim3(8, 32), 256, 0, stream>>>(hb, wT, p_outb, xf, xf, nullptr, 4096, 1024, 1024, flag);

  // ---- MLP block ----
  ln_kernel<<<4096, 256, 0, stream>>>(xf, p_ln3w, p_ln3b, hb);
  transpose_k<<<dim3(128, 32), 256, 0, stream>>>(mlp1_w, wT, 1024, 4096, flag);
  gemm_tn<2><<<dim3(32, 32), 256, 0, stream>>>(hb, wT, p_m1b, nullptr, nullptr, big, 4096, 4096, 1024, flag);
  transpose_k<<<dim3(32, 128), 256, 0, stream>>>(mlp2_w, wT, 4096, 1024, flag);
  gemm_tn<3><<<dim3(8, 32), 256, 0, stream>>>(big, wT, p_m2b, xf, nullptr, d_out, 4096, 1024, 4096, flag);
}

// Round 4
// 654.592 us; speedup vs baseline: 4.9103x; 4.9103x over previous
//
#include <hip/hip_runtime.h>
#include <hip/hip_bf16.h>

typedef unsigned short u16;
typedef __bf16 bf16x8 __attribute__((ext_vector_type(8)));
typedef float f32x4 __attribute__((ext_vector_type(4)));

__device__ __forceinline__ float bf2f(u16 v) { return __uint_as_float(((unsigned)v) << 16); }
__device__ __forceinline__ u16 f2bf(float f) {
  unsigned u = __float_as_uint(f);
  u += 0x7FFFu + ((u >> 16) & 1u);
  return (u16)(u >> 16);
}
__device__ __forceinline__ float gelu_exact(float x) {
  return 0.5f * x * (1.0f + erff(x * 0.70710678118654752f));
}

// ---------------- dtype sniffer (1 = bf16, 0 = fp32) ----------------
__global__ void sniff_kernel(const u16* __restrict__ x, int* __restrict__ flag) {
  int tid = threadIdx.x;  // 64
  int hits = 0;
  #pragma unroll
  for (int s = 0; s < 2; ++s) {
    float f = fabsf(bf2f(x[2 * (tid + 64 * s)]));
    hits += (f >= 0.00390625f && f <= 16.0f) ? 1 : 0;
  }
  #pragma unroll
  for (int off = 32; off; off >>= 1) hits += __shfl_xor(hits, off);
  if (tid == 0) flag[0] = (hits >= 64) ? 1 : 0;
}

// ---------------- input -> bf16 copy/convert ----------------
__global__ __launch_bounds__(256) void in2bf_kernel(const void* __restrict__ src, u16* __restrict__ dst,
                                                    int n4, const int* __restrict__ flagp) {
  int i = blockIdx.x * 256 + threadIdx.x;
  if (i >= n4) return;
  if (*flagp) {
    ((ushort4*)dst)[i] = ((const ushort4*)src)[i];
  } else {
    float4 v = ((const float4*)src)[i];
    ushort4 o; o.x = f2bf(v.x); o.y = f2bf(v.y); o.z = f2bf(v.z); o.w = f2bf(v.w);
    ((ushort4*)dst)[i] = o;
  }
}

// ---------------- input -> fp32 copy/convert (residual stream init) ----------------
__global__ __launch_bounds__(256) void in2f32_kernel(const void* __restrict__ src, float* __restrict__ dst,
                                                     int n4, const int* __restrict__ flagp) {
  int i = blockIdx.x * 256 + threadIdx.x;
  if (i >= n4) return;
  if (*flagp) {
    ushort4 v = ((const ushort4*)src)[i];
    float4 o; o.x = bf2f(v.x); o.y = bf2f(v.y); o.z = bf2f(v.z); o.w = bf2f(v.w);
    ((float4*)dst)[i] = o;
  } else {
    ((float4*)dst)[i] = ((const float4*)src)[i];
  }
}

// ---------------- weight transpose: in [R,C] -> out [C,R] bf16, dual-dtype read ----------------
__global__ __launch_bounds__(256) void transpose_k(const void* __restrict__ in_, u16* __restrict__ out,
                                                   int R, int C, const int* __restrict__ flagp) {
  int flag = *flagp;
  __shared__ u16 tile[32][33];
  int c0 = blockIdx.x * 32, r0 = blockIdx.y * 32;
  int tx = threadIdx.x & 31, ty = threadIdx.x >> 5;
  #pragma unroll
  for (int j = 0; j < 32; j += 8) {
    size_t idx = (size_t)(r0 + ty + j) * C + c0 + tx;
    tile[ty + j][tx] = flag ? ((const u16*)in_)[idx] : f2bf(((const float*)in_)[idx]);
  }
  __syncthreads();
  #pragma unroll
  for (int j = 0; j < 32; j += 8)
    out[(size_t)(c0 + ty + j) * R + r0 + tx] = tile[tx][ty + j];
}

// ---------------- LayerNorm: fp32 in -> bf16 out, D=1024 ----------------
__global__ __launch_bounds__(256) void ln_kernel(const float* __restrict__ x,
                                                 const u16* __restrict__ w, const u16* __restrict__ b,
                                                 u16* __restrict__ out) {
  int row = blockIdx.x, tid = threadIdx.x;
  float4 v = ((const float4*)(x + (size_t)row * 1024))[tid];
  float s = v.x + v.y + v.z + v.w;
  #pragma unroll
  for (int off = 32; off; off >>= 1) s += __shfl_xor(s, off);
  __shared__ float red1[4], red2[4];
  if ((tid & 63) == 0) red1[tid >> 6] = s;
  __syncthreads();
  float mean = (red1[0] + red1[1] + red1[2] + red1[3]) * (1.0f / 1024.0f);
  float d0 = v.x - mean, d1 = v.y - mean, d2 = v.z - mean, d3 = v.w - mean;
  float vs = d0 * d0 + d1 * d1 + d2 * d2 + d3 * d3;
  #pragma unroll
  for (int off = 32; off; off >>= 1) vs += __shfl_xor(vs, off);
  if ((tid & 63) == 0) red2[tid >> 6] = vs;
  __syncthreads();
  float var = (red2[0] + red2[1] + red2[2] + red2[3]) * (1.0f / 1024.0f);
  float rs = rsqrtf(var + 1e-5f);
  int c = tid * 4;
  ushort4 o;
  o.x = f2bf(d0 * rs * bf2f(w[c + 0]) + bf2f(b[c + 0]));
  o.y = f2bf(d1 * rs * bf2f(w[c + 1]) + bf2f(b[c + 1]));
  o.z = f2bf(d2 * rs * bf2f(w[c + 2]) + bf2f(b[c + 2]));
  o.w = f2bf(d3 * rs * bf2f(w[c + 3]) + bf2f(b[c + 3]));
  ((ushort4*)(out + (size_t)row * 1024))[tid] = o;
}

// ---------------- TN GEMM: C[M,N] = A[M,K] @ Bt[N,K]^T + bias, bf16 MFMA ----------------
#define LDK 72

template <int MODE>
__global__ __launch_bounds__(256) void gemm_tn(const u16* __restrict__ A, const u16* __restrict__ Bt,
                                               const u16* __restrict__ bias,
                                               const float* __restrict__ resid_in, float* __restrict__ resid_out,
                                               void* __restrict__ outp, int M, int N, int K,
                                               const int* __restrict__ flagp) {
  __shared__ __align__(16) u16 As[128 * LDK];
  __shared__ __align__(16) u16 Bs[128 * LDK];
  int n0 = blockIdx.x * 128, m0 = blockIdx.y * 128;
  int tid = threadIdx.x;
  int lane = tid & 63, w = tid >> 6;
  int wm = w & 1, wn = w >> 1;
  int flag = (MODE == 3) ? *flagp : 0;
  f32x4 acc[4][4];
  #pragma unroll
  for (int i = 0; i < 4; i++)
    #pragma unroll
    for (int j = 0; j < 4; j++) acc[i][j] = (f32x4){0.f, 0.f, 0.f, 0.f};

  int trow = tid >> 3, tcol = tid & 7;
  for (int k0 = 0; k0 < K; k0 += 64) {
    #pragma unroll
    for (int r = 0; r < 4; ++r) {
      int row = trow + 32 * r;
      *(uint4*)&As[row * LDK + tcol * 8] = *(const uint4*)&A[(size_t)(m0 + row) * K + k0 + tcol * 8];
      *(uint4*)&Bs[row * LDK + tcol * 8] = *(const uint4*)&Bt[(size_t)(n0 + row) * K + k0 + tcol * 8];
    }
    __syncthreads();
    #pragma unroll
    for (int kk = 0; kk < 64; kk += 32) {
      int kidx = kk + (lane >> 4) * 8;
      bf16x8 af[4], bfr[4];
      #pragma unroll
      for (int i = 0; i < 4; i++) {
        af[i]  = *(const bf16x8*)&As[(wm * 64 + i * 16 + (lane & 15)) * LDK + kidx];
        bfr[i] = *(const bf16x8*)&Bs[(wn * 64 + i * 16 + (lane & 15)) * LDK + kidx];
      }
      #pragma unroll
      for (int mi = 0; mi < 4; mi++)
        #pragma unroll
        for (int ni = 0; ni < 4; ni++)
          acc[mi][ni] = __builtin_amdgcn_mfma_f32_16x16x32_bf16(af[mi], bfr[ni], acc[mi][ni], 0, 0, 0);
    }
    __syncthreads();
  }
  int col_base = n0 + wn * 64, row_base = m0 + wm * 64;
  #pragma unroll
  for (int mi = 0; mi < 4; mi++) {
    #pragma unroll
    for (int ni = 0; ni < 4; ni++) {
      int col = col_base + ni * 16 + (lane & 15);
      float bv = bf2f(bias[col]);
      #pragma unroll
      for (int r = 0; r < 4; r++) {
        int row = row_base + mi * 16 + (lane >> 4) * 4 + r;
        float vv = acc[mi][ni][r] + bv;
        size_t idx = (size_t)row * N + col;
        if (MODE == 0) ((u16*)outp)[idx] = f2bf(vv);
        else if (MODE == 1) resid_out[idx] = resid_in[idx] + vv;
        else if (MODE == 2) ((u16*)outp)[idx] = f2bf(gelu_exact(vv));
        else {
          float ov = resid_in[idx] + vv;
          if (flag) ((u16*)outp)[idx] = f2bf(ov);
          else ((float*)outp)[idx] = ov;
        }
      }
    }
  }
}

// ---------------- MFMA flash attention, HD=64 ----------------
// grid: (T/64, B*H); 256 threads = 4 waves; each wave owns 16 query rows.
// Fragment layouts identical to gemm_tn (verified): A/B frag = row (lane&15), k = (lane>>4)*8;
// C/D: col = lane&15 (+16*ni), row = (lane>>4)*4 + r.
__global__ __launch_bounds__(256) void attn_mfma(const u16* __restrict__ Q, const u16* __restrict__ K,
                                                 const u16* __restrict__ V, u16* __restrict__ O,
                                                 int T, int S, int qstride, int kstride, int causal) {
  int bh = blockIdx.y, b = bh >> 4, h = bh & 15;
  const u16* Qb = Q + (size_t)b * T * qstride + h * 64;
  const u16* Kb = K + (size_t)b * S * kstride + h * 64;
  const u16* Vb = V + (size_t)b * S * kstride + h * 64;
  u16* Ob = O + (size_t)b * T * 1024 + h * 64;

  int tid = threadIdx.x, lane = tid & 63, w = tid >> 6;
  int quad = lane >> 4, l15 = lane & 15;
  int qt = blockIdx.x * 64;

  __shared__ __align__(16) u16 Ks[64 * 72];
  __shared__ __align__(16) u16 Vt[64 * 72];
  __shared__ __align__(16) u16 Ps[4][16 * 72];

  int sr = tid >> 2, sc0 = (tid & 3) * 16;  // staging: row, col-base (16 elems/thread)

  // ---- stage Q tile via Ks, load persistent Q fragments ----
  *(uint4*)&Ks[sr * 72 + sc0]     = *(const uint4*)&Qb[(size_t)(qt + sr) * qstride + sc0];
  *(uint4*)&Ks[sr * 72 + sc0 + 8] = *(const uint4*)&Qb[(size_t)(qt + sr) * qstride + sc0 + 8];
  __syncthreads();
  bf16x8 qfrag[2];
  #pragma unroll
  for (int c = 0; c < 2; ++c)
    qfrag[c] = *(const bf16x8*)&Ks[(w * 16 + l15) * 72 + c * 32 + quad * 8];

  float m_i[4], l_i[4];
  f32x4 oacc[4];
  #pragma unroll
  for (int r = 0; r < 4; ++r) { m_i[r] = -1e30f; l_i[r] = 0.f; }
  #pragma unroll
  for (int ni = 0; ni < 4; ++ni) oacc[ni] = (f32x4){0.f, 0.f, 0.f, 0.f};

  int nk = causal ? (blockIdx.x + 1) * 64 : S;
  int tg0 = qt + w * 16 + quad * 4;  // global query row for r=0

  for (int s0 = 0; s0 < nk; s0 += 64) {
    __syncthreads();  // previous compute done before restaging
    // ---- stage K tile + V tile transposed ----
    *(uint4*)&Ks[sr * 72 + sc0]     = *(const uint4*)&Kb[(size_t)(s0 + sr) * kstride + sc0];
    *(uint4*)&Ks[sr * 72 + sc0 + 8] = *(const uint4*)&Kb[(size_t)(s0 + sr) * kstride + sc0 + 8];
    uint4 v0 = *(const uint4*)&Vb[(size_t)(s0 + sr) * kstride + sc0];
    uint4 v1 = *(const uint4*)&Vb[(size_t)(s0 + sr) * kstride + sc0 + 8];
    union { uint4 u[2]; u16 e[16]; } vv; vv.u[0] = v0; vv.u[1] = v1;
    #pragma unroll
    for (int j = 0; j < 16; ++j) Vt[(sc0 + j) * 72 + sr] = vv.e[j];
    __syncthreads();

    // ---- S = Q K^T ----
    f32x4 sacc[4];
    #pragma unroll
    for (int ni = 0; ni < 4; ++ni) sacc[ni] = (f32x4){0.f, 0.f, 0.f, 0.f};
    #pragma unroll
    for (int c = 0; c < 2; ++c) {
      #pragma unroll
      for (int ni = 0; ni < 4; ++ni) {
        bf16x8 kf = *(const bf16x8*)&Ks[(ni * 16 + l15) * 72 + c * 32 + quad * 8];
        sacc[ni] = __builtin_amdgcn_mfma_f32_16x16x32_bf16(qfrag[c], kf, sacc[ni], 0, 0, 0);
      }
    }

    // ---- scale + causal mask ----
    #pragma unroll
    for (int ni = 0; ni < 4; ++ni) {
      int key = s0 + ni * 16 + l15;
      #pragma unroll
      for (int r = 0; r < 4; ++r) {
        float sv = sacc[ni][r] * 0.125f;
        if (causal && key > tg0 + r) sv = -1e30f;
        sacc[ni][r] = sv;
      }
    }

    // ---- online softmax ----
    float mnew[4], alpha[4], psum[4];
    #pragma unroll
    for (int r = 0; r < 4; ++r) {
      float mx = fmaxf(fmaxf(sacc[0][r], sacc[1][r]), fmaxf(sacc[2][r], sacc[3][r]));
      #pragma unroll
      for (int off = 1; off < 16; off <<= 1) mx = fmaxf(mx, __shfl_xor(mx, off));
      mnew[r] = fmaxf(m_i[r], mx);
      alpha[r] = __expf(m_i[r] - mnew[r]);
      m_i[r] = mnew[r];
      psum[r] = 0.f;
    }
    #pragma unroll
    for (int ni = 0; ni < 4; ++ni) {
      #pragma unroll
      for (int r = 0; r < 4; ++r) {
        float p = __expf(sacc[ni][r] - mnew[r]);
        psum[r] += p;
        Ps[w][(quad * 4 + r) * 72 + ni * 16 + l15] = f2bf(p);
      }
    }
    #pragma unroll
    for (int r = 0; r < 4; ++r) {
      float ps = psum[r];
      #pragma unroll
      for (int off = 1; off < 16; off <<= 1) ps += __shfl_xor(ps, off);
      l_i[r] = l_i[r] * alpha[r] + ps;
    }

    // ---- P -> A-layout (per-wave LDS roundtrip; no cross-wave hazard) ----
    bf16x8 pfrag[2];
    #pragma unroll
    for (int c = 0; c < 2; ++c)
      pfrag[c] = *(const bf16x8*)&Ps[w][l15 * 72 + c * 32 + quad * 8];

    // ---- O = O*alpha + P V ----
    #pragma unroll
    for (int ni = 0; ni < 4; ++ni)
      #pragma unroll
      for (int r = 0; r < 4; ++r) oacc[ni][r] *= alpha[r];
    #pragma unroll
    for (int c = 0; c < 2; ++c) {
      #pragma unroll
      for (int ni = 0; ni < 4; ++ni) {
        bf16x8 vf = *(const bf16x8*)&Vt[(ni * 16 + l15) * 72 + c * 32 + quad * 8];
        oacc[ni] = __builtin_amdgcn_mfma_f32_16x16x32_bf16(pfrag[c], vf, oacc[ni], 0, 0, 0);
      }
    }
  }

  // ---- epilogue ----
  #pragma unroll
  for (int ni = 0; ni < 4; ++ni) {
    #pragma unroll
    for (int r = 0; r < 4; ++r) {
      int t = tg0 + r;
      int d = ni * 16 + l15;
      Ob[(size_t)t * 1024 + d] = f2bf(oacc[ni][r] / l_i[r]);
    }
  }
}

extern "C" void kernel_launch(void* const* d_in, const int* in_sizes, int n_in,
                              void* d_out, int out_size, void* d_ws, size_t ws_size,
                              hipStream_t stream) {
  const void* x_in   = d_in[0];
  const void* enc_in = d_in[1];
  const void* ln1_w = d_in[4];  const void* ln1_b = d_in[5];
  const void* qkv_w = d_in[6];  const void* qkv_b = d_in[7];
  const void* proj_w = d_in[8]; const void* proj_b = d_in[9];
  const void* ln2_w = d_in[10]; const void* ln2_b = d_in[11];
  const void* q_w = d_in[12];   const void* q_b = d_in[13];
  const void* k_w = d_in[14];   const void* k_b = d_in[15];
  const void* v_w = d_in[16];   const void* v_b = d_in[17];
  const void* out_w = d_in[18]; const void* out_b = d_in[19];
  const void* ln3_w = d_in[20]; const void* ln3_b = d_in[21];
  const void* mlp1_w = d_in[22]; const void* mlp1_b = d_in[23];
  const void* mlp2_w = d_in[24]; const void* mlp2_b = d_in[25];

  char* ws = (char*)d_ws;
  size_t off = 0;
  auto alloc = [&](size_t bytes) { char* p = ws + off; off += (bytes + 255) & ~(size_t)255; return p; };
  float* xf   = (float*)alloc(4096ull * 1024 * 4);
  u16* hb     = (u16*)alloc(4096ull * 1024 * 2);
  u16* big    = (u16*)alloc(4096ull * 4096 * 2);
  u16* wT     = (u16*)alloc(3072ull * 1024 * 2);
  u16* encb   = (u16*)alloc(2304ull * 768 * 2);
  u16* pool   = (u16*)alloc(20480ull * 2);
  int* flag   = (int*)alloc(256);
  (void)ws_size;

  u16* q_bf = big;
  u16* k_bf = big + 4096ull * 1024;
  u16* v_bf = big + (4096ull + 2304) * 1024;

  u16 *p_ln1w = pool, *p_ln1b = pool + 1024, *p_ln2w = pool + 2048, *p_ln2b = pool + 3072;
  u16 *p_ln3w = pool + 4096, *p_ln3b = pool + 5120;
  u16 *p_qkvb = pool + 6144, *p_projb = pool + 9216, *p_qb = pool + 10240, *p_kb = pool + 11264;
  u16 *p_vb = pool + 12288, *p_outb = pool + 13312, *p_m1b = pool + 14336, *p_m2b = pool + 18432;

  // ---- dtype sniff + input conversion ----
  sniff_kernel<<<1, 64, 0, stream>>>((const u16*)x_in, flag);
  in2f32_kernel<<<4096, 256, 0, stream>>>(x_in, xf, 1048576, flag);
  in2bf_kernel<<<1728, 256, 0, stream>>>(enc_in, encb, 442368, flag);
  in2bf_kernel<<<1, 256, 0, stream>>>(ln1_w, p_ln1w, 256, flag);
  in2bf_kernel<<<1, 256, 0, stream>>>(ln1_b, p_ln1b, 256, flag);
  in2bf_kernel<<<1, 256, 0, stream>>>(ln2_w, p_ln2w, 256, flag);
  in2bf_kernel<<<1, 256, 0, stream>>>(ln2_b, p_ln2b, 256, flag);
  in2bf_kernel<<<1, 256, 0, stream>>>(ln3_w, p_ln3w, 256, flag);
  in2bf_kernel<<<1, 256, 0, stream>>>(ln3_b, p_ln3b, 256, flag);
  in2bf_kernel<<<3, 256, 0, stream>>>(qkv_b, p_qkvb, 768, flag);
  in2bf_kernel<<<1, 256, 0, stream>>>(proj_b, p_projb, 256, flag);
  in2bf_kernel<<<1, 256, 0, stream>>>(q_b, p_qb, 256, flag);
  in2bf_kernel<<<1, 256, 0, stream>>>(k_b, p_kb, 256, flag);
  in2bf_kernel<<<1, 256, 0, stream>>>(v_b, p_vb, 256, flag);
  in2bf_kernel<<<1, 256, 0, stream>>>(out_b, p_outb, 256, flag);
  in2bf_kernel<<<4, 256, 0, stream>>>(mlp1_b, p_m1b, 1024, flag);
  in2bf_kernel<<<1, 256, 0, stream>>>(mlp2_b, p_m2b, 256, flag);

  // ---- self-attention block ----
  ln_kernel<<<4096, 256, 0, stream>>>(xf, p_ln1w, p_ln1b, hb);
  transpose_k<<<dim3(96, 32), 256, 0, stream>>>(qkv_w, wT, 1024, 3072, flag);
  gemm_tn<0><<<dim3(24, 32), 256, 0, stream>>>(hb, wT, p_qkvb, nullptr, nullptr, big, 4096, 3072, 1024, flag);
  attn_mfma<<<dim3(16, 64), 256, 0, stream>>>(big, big + 1024, big + 2048, hb, 1024, 1024, 3072, 3072, 1);
  transpose_k<<<dim3(32, 32), 256, 0, stream>>>(proj_w, wT, 1024, 1024, flag);
  gemm_tn<1><<<dim3(8, 32), 256, 0, stream>>>(hb, wT, p_projb, xf, xf, nullptr, 4096, 1024, 1024, flag);

  // ---- cross-attention block ----
  ln_kernel<<<4096, 256, 0, stream>>>(xf, p_ln2w, p_ln2b, hb);
  transpose_k<<<dim3(32, 32), 256, 0, stream>>>(q_w, wT, 1024, 1024, flag);
  gemm_tn<0><<<dim3(8, 32), 256, 0, stream>>>(hb, wT, p_qb, nullptr, nullptr, q_bf, 4096, 1024, 1024, flag);
  transpose_k<<<dim3(32, 24), 256, 0, stream>>>(k_w, wT, 768, 1024, flag);
  gemm_tn<0><<<dim3(8, 18), 256, 0, stream>>>(encb, wT, p_kb, nullptr, nullptr, k_bf, 2304, 1024, 768, flag);
  transpose_k<<<dim3(32, 24), 256, 0, stream>>>(v_w, wT, 768, 1024, flag);
  gemm_tn<0><<<dim3(8, 18), 256, 0, stream>>>(encb, wT, p_vb, nullptr, nullptr, v_bf, 2304, 1024, 768, flag);
  attn_mfma<<<dim3(16, 64), 256, 0, stream>>>(q_bf, k_bf, v_bf, hb, 1024, 576, 1024, 1024, 0);
  transpose_k<<<dim3(32, 32), 256, 0, stream>>>(out_w, wT, 1024, 1024, flag);
  gemm_tn<1><<<dim3(8, 32), 256, 0, stream>>>(hb, wT, p_outb, xf, xf, nullptr, 4096, 1024, 1024, flag);

  // ---- MLP block ----
  ln_kernel<<<4096, 256, 0, stream>>>(xf, p_ln3w, p_ln3b, hb);
  transpose_k<<<dim3(128, 32), 256, 0, stream>>>(mlp1_w, wT, 1024, 4096, flag);
  gemm_tn<2><<<dim3(32, 32), 256, 0, stream>>>(hb, wT, p_m1b, nullptr, nullptr, big, 4096, 4096, 1024, flag);
  transpose_k<<<dim3(32, 128), 256, 0, stream>>>(mlp2_w, wT, 4096, 1024, flag);
  gemm_tn<3><<<dim3(8, 32), 256, 0, stream>>>(big, wT, p_m2b, xf, nullptr, d_out, 4096, 1024, 4096, flag);
}

// Round 5
// 654.075 us; speedup vs baseline: 4.9141x; 1.0008x over previous
//
#include <hip/hip_runtime.h>
#include <hip/hip_bf16.h>

typedef unsigned short u16;
typedef __bf16 bf16x8 __attribute__((ext_vector_type(8)));
typedef float f32x4 __attribute__((ext_vector_type(4)));

__device__ __forceinline__ float bf2f(u16 v) { return __uint_as_float(((unsigned)v) << 16); }
__device__ __forceinline__ u16 f2bf(float f) {
  unsigned u = __float_as_uint(f);
  u += 0x7FFFu + ((u >> 16) & 1u);
  return (u16)(u >> 16);
}
__device__ __forceinline__ float gelu_exact(float x) {
  return 0.5f * x * (1.0f + erff(x * 0.70710678118654752f));
}

// async global->LDS DMA, 16B per lane; LDS dest = wave-uniform base + lane*16
__device__ __forceinline__ void async_load16(const u16* g, u16* l) {
  __builtin_amdgcn_global_load_lds((const __attribute__((address_space(1))) void*)g,
                                   (__attribute__((address_space(3))) void*)l, 16, 0, 0);
}

// ---------------- dtype sniffer (1 = bf16, 0 = fp32) ----------------
__global__ void sniff_kernel(const u16* __restrict__ x, int* __restrict__ flag) {
  int tid = threadIdx.x;  // 64
  int hits = 0;
  #pragma unroll
  for (int s = 0; s < 2; ++s) {
    float f = fabsf(bf2f(x[2 * (tid + 64 * s)]));
    hits += (f >= 0.00390625f && f <= 16.0f) ? 1 : 0;
  }
  #pragma unroll
  for (int off = 32; off; off >>= 1) hits += __shfl_xor(hits, off);
  if (tid == 0) flag[0] = (hits >= 64) ? 1 : 0;
}

// ---------------- input -> bf16 copy/convert ----------------
__global__ __launch_bounds__(256) void in2bf_kernel(const void* __restrict__ src, u16* __restrict__ dst,
                                                    int n4, const int* __restrict__ flagp) {
  int i = blockIdx.x * 256 + threadIdx.x;
  if (i >= n4) return;
  if (*flagp) {
    ((ushort4*)dst)[i] = ((const ushort4*)src)[i];
  } else {
    float4 v = ((const float4*)src)[i];
    ushort4 o; o.x = f2bf(v.x); o.y = f2bf(v.y); o.z = f2bf(v.z); o.w = f2bf(v.w);
    ((ushort4*)dst)[i] = o;
  }
}

// ---------------- input -> fp32 copy/convert (residual stream init) ----------------
__global__ __launch_bounds__(256) void in2f32_kernel(const void* __restrict__ src, float* __restrict__ dst,
                                                     int n4, const int* __restrict__ flagp) {
  int i = blockIdx.x * 256 + threadIdx.x;
  if (i >= n4) return;
  if (*flagp) {
    ushort4 v = ((const ushort4*)src)[i];
    float4 o; o.x = bf2f(v.x); o.y = bf2f(v.y); o.z = bf2f(v.z); o.w = bf2f(v.w);
    ((float4*)dst)[i] = o;
  } else {
    ((float4*)dst)[i] = ((const float4*)src)[i];
  }
}

// ---------------- weight transpose: in [R,C] -> out [C,R] bf16, dual-dtype read ----------------
__global__ __launch_bounds__(256) void transpose_k(const void* __restrict__ in_, u16* __restrict__ out,
                                                   int R, int C, const int* __restrict__ flagp) {
  int flag = *flagp;
  __shared__ u16 tile[32][33];
  int c0 = blockIdx.x * 32, r0 = blockIdx.y * 32;
  int tx = threadIdx.x & 31, ty = threadIdx.x >> 5;
  #pragma unroll
  for (int j = 0; j < 32; j += 8) {
    size_t idx = (size_t)(r0 + ty + j) * C + c0 + tx;
    tile[ty + j][tx] = flag ? ((const u16*)in_)[idx] : f2bf(((const float*)in_)[idx]);
  }
  __syncthreads();
  #pragma unroll
  for (int j = 0; j < 32; j += 8)
    out[(size_t)(c0 + ty + j) * R + r0 + tx] = tile[tx][ty + j];
}

// ---------------- LayerNorm: fp32 in -> bf16 out, D=1024 ----------------
__global__ __launch_bounds__(256) void ln_kernel(const float* __restrict__ x,
                                                 const u16* __restrict__ w, const u16* __restrict__ b,
                                                 u16* __restrict__ out) {
  int row = blockIdx.x, tid = threadIdx.x;
  float4 v = ((const float4*)(x + (size_t)row * 1024))[tid];
  float s = v.x + v.y + v.z + v.w;
  #pragma unroll
  for (int off = 32; off; off >>= 1) s += __shfl_xor(s, off);
  __shared__ float red1[4], red2[4];
  if ((tid & 63) == 0) red1[tid >> 6] = s;
  __syncthreads();
  float mean = (red1[0] + red1[1] + red1[2] + red1[3]) * (1.0f / 1024.0f);
  float d0 = v.x - mean, d1 = v.y - mean, d2 = v.z - mean, d3 = v.w - mean;
  float vs = d0 * d0 + d1 * d1 + d2 * d2 + d3 * d3;
  #pragma unroll
  for (int off = 32; off; off >>= 1) vs += __shfl_xor(vs, off);
  if ((tid & 63) == 0) red2[tid >> 6] = vs;
  __syncthreads();
  float var = (red2[0] + red2[1] + red2[2] + red2[3]) * (1.0f / 1024.0f);
  float rs = rsqrtf(var + 1e-5f);
  int c = tid * 4;
  ushort4 o;
  o.x = f2bf(d0 * rs * bf2f(w[c + 0]) + bf2f(b[c + 0]));
  o.y = f2bf(d1 * rs * bf2f(w[c + 1]) + bf2f(b[c + 1]));
  o.z = f2bf(d2 * rs * bf2f(w[c + 2]) + bf2f(b[c + 2]));
  o.w = f2bf(d3 * rs * bf2f(w[c + 3]) + bf2f(b[c + 3]));
  ((ushort4*)(out + (size_t)row * 1024))[tid] = o;
}

// ---------------- TN GEMM: C[M,N] = A[M,K] @ Bt[N,K]^T + bias, bf16 MFMA ----------------
// Staging via global_load_lds (16B/lane DMA) with XOR-swizzled k-blocks:
//   LDS slot s (16B) of row r holds global k-block s ^ (r&7)  -> 2-way banks (free), no pad.
// MODE 0: out = bf16(r);  1: resid_out = resid_in + r (fp32);  2: out = bf16(gelu(r));
// MODE 3: out = resid_in + r stored per *flagp (bf16/fp32)
template <int MODE>
__global__ __launch_bounds__(256) void gemm_tn(const u16* __restrict__ A, const u16* __restrict__ Bt,
                                               const u16* __restrict__ bias,
                                               const float* __restrict__ resid_in, float* __restrict__ resid_out,
                                               void* __restrict__ outp, int M, int N, int K,
                                               const int* __restrict__ flagp) {
  __shared__ __align__(16) u16 As[128 * 64];
  __shared__ __align__(16) u16 Bs[128 * 64];
  int n0 = blockIdx.x * 128, m0 = blockIdx.y * 128;
  int tid = threadIdx.x;
  int lane = tid & 63, w = tid >> 6;
  int wm = w & 1, wn = w >> 1;
  int quad = lane >> 4, l15 = lane & 15;
  int sw = l15 & 7;  // fragment-read swizzle key (row & 7)
  int flag = (MODE == 3) ? *flagp : 0;
  f32x4 acc[4][4];
  #pragma unroll
  for (int i = 0; i < 4; i++)
    #pragma unroll
    for (int j = 0; j < 4; j++) acc[i][j] = (f32x4){0.f, 0.f, 0.f, 0.f};

  // staging geometry: lane covers row (lane>>3) of an 8-row group, swizzled k-block
  int srow8 = lane >> 3;
  int scol = ((lane & 7) ^ srow8) * 8;  // u16 offset of fetched k-block
  const u16* Abase = A + (size_t)(m0 + srow8) * K + scol;
  const u16* Bbase = Bt + (size_t)(n0 + srow8) * K + scol;

  for (int k0 = 0; k0 < K; k0 += 64) {
    #pragma unroll
    for (int j = 0; j < 4; ++j) {
      int r0 = (w * 4 + j) * 8;
      async_load16(Abase + (size_t)r0 * K + k0, &As[r0 * 64]);
      async_load16(Bbase + (size_t)r0 * K + k0, &Bs[r0 * 64]);
    }
    __syncthreads();  // drains vmcnt (compiler emits waitcnt before barrier)
    #pragma unroll
    for (int kk = 0; kk < 64; kk += 32) {
      int cbase = (kk >> 3) + quad;  // k-block index 0..7
      int slot = (cbase ^ sw) << 3;  // swizzled LDS u16 offset
      bf16x8 af[4], bfr[4];
      #pragma unroll
      for (int i = 0; i < 4; i++) {
        af[i]  = *(const bf16x8*)&As[(wm * 64 + i * 16 + l15) * 64 + slot];
        bfr[i] = *(const bf16x8*)&Bs[(wn * 64 + i * 16 + l15) * 64 + slot];
      }
      #pragma unroll
      for (int mi = 0; mi < 4; mi++)
        #pragma unroll
        for (int ni = 0; ni < 4; ni++)
          acc[mi][ni] = __builtin_amdgcn_mfma_f32_16x16x32_bf16(af[mi], bfr[ni], acc[mi][ni], 0, 0, 0);
    }
    __syncthreads();
  }
  int col_base = n0 + wn * 64, row_base = m0 + wm * 64;
  #pragma unroll
  for (int mi = 0; mi < 4; mi++) {
    #pragma unroll
    for (int ni = 0; ni < 4; ni++) {
      int col = col_base + ni * 16 + l15;
      float bv = bf2f(bias[col]);
      #pragma unroll
      for (int r = 0; r < 4; r++) {
        int row = row_base + mi * 16 + quad * 4 + r;
        float vv = acc[mi][ni][r] + bv;
        size_t idx = (size_t)row * N + col;
        if (MODE == 0) ((u16*)outp)[idx] = f2bf(vv);
        else if (MODE == 1) resid_out[idx] = resid_in[idx] + vv;
        else if (MODE == 2) ((u16*)outp)[idx] = f2bf(gelu_exact(vv));
        else {
          float ov = resid_in[idx] + vv;
          if (flag) ((u16*)outp)[idx] = f2bf(ov);
          else ((float*)outp)[idx] = ov;
        }
      }
    }
  }
}

// ---------------- MFMA flash attention, HD=64 ----------------
__global__ __launch_bounds__(256) void attn_mfma(const u16* __restrict__ Q, const u16* __restrict__ K,
                                                 const u16* __restrict__ V, u16* __restrict__ O,
                                                 int T, int S, int qstride, int kstride, int causal) {
  int bh = blockIdx.y, b = bh >> 4, h = bh & 15;
  const u16* Qb = Q + (size_t)b * T * qstride + h * 64;
  const u16* Kb = K + (size_t)b * S * kstride + h * 64;
  const u16* Vb = V + (size_t)b * S * kstride + h * 64;
  u16* Ob = O + (size_t)b * T * 1024 + h * 64;

  int tid = threadIdx.x, lane = tid & 63, w = tid >> 6;
  int quad = lane >> 4, l15 = lane & 15;
  int qt = blockIdx.x * 64;

  __shared__ __align__(16) u16 Ks[64 * 72];
  __shared__ __align__(16) u16 Vt[64 * 72];
  __shared__ __align__(16) u16 Ps[4][16 * 72];

  int sr = tid >> 2, sc0 = (tid & 3) * 16;

  *(uint4*)&Ks[sr * 72 + sc0]     = *(const uint4*)&Qb[(size_t)(qt + sr) * qstride + sc0];
  *(uint4*)&Ks[sr * 72 + sc0 + 8] = *(const uint4*)&Qb[(size_t)(qt + sr) * qstride + sc0 + 8];
  __syncthreads();
  bf16x8 qfrag[2];
  #pragma unroll
  for (int c = 0; c < 2; ++c)
    qfrag[c] = *(const bf16x8*)&Ks[(w * 16 + l15) * 72 + c * 32 + quad * 8];

  float m_i[4], l_i[4];
  f32x4 oacc[4];
  #pragma unroll
  for (int r = 0; r < 4; ++r) { m_i[r] = -1e30f; l_i[r] = 0.f; }
  #pragma unroll
  for (int ni = 0; ni < 4; ++ni) oacc[ni] = (f32x4){0.f, 0.f, 0.f, 0.f};

  int nk = causal ? (blockIdx.x + 1) * 64 : S;
  int tg0 = qt + w * 16 + quad * 4;

  for (int s0 = 0; s0 < nk; s0 += 64) {
    __syncthreads();
    *(uint4*)&Ks[sr * 72 + sc0]     = *(const uint4*)&Kb[(size_t)(s0 + sr) * kstride + sc0];
    *(uint4*)&Ks[sr * 72 + sc0 + 8] = *(const uint4*)&Kb[(size_t)(s0 + sr) * kstride + sc0 + 8];
    uint4 v0 = *(const uint4*)&Vb[(size_t)(s0 + sr) * kstride + sc0];
    uint4 v1 = *(const uint4*)&Vb[(size_t)(s0 + sr) * kstride + sc0 + 8];
    union { uint4 u[2]; u16 e[16]; } vv; vv.u[0] = v0; vv.u[1] = v1;
    #pragma unroll
    for (int j = 0; j < 16; ++j) Vt[(sc0 + j) * 72 + sr] = vv.e[j];
    __syncthreads();

    f32x4 sacc[4];
    #pragma unroll
    for (int ni = 0; ni < 4; ++ni) sacc[ni] = (f32x4){0.f, 0.f, 0.f, 0.f};
    #pragma unroll
    for (int c = 0; c < 2; ++c) {
      #pragma unroll
      for (int ni = 0; ni < 4; ++ni) {
        bf16x8 kf = *(const bf16x8*)&Ks[(ni * 16 + l15) * 72 + c * 32 + quad * 8];
        sacc[ni] = __builtin_amdgcn_mfma_f32_16x16x32_bf16(qfrag[c], kf, sacc[ni], 0, 0, 0);
      }
    }

    #pragma unroll
    for (int ni = 0; ni < 4; ++ni) {
      int key = s0 + ni * 16 + l15;
      #pragma unroll
      for (int r = 0; r < 4; ++r) {
        float sv = sacc[ni][r] * 0.125f;
        if (causal && key > tg0 + r) sv = -1e30f;
        sacc[ni][r] = sv;
      }
    }

    float mnew[4], alpha[4], psum[4];
    #pragma unroll
    for (int r = 0; r < 4; ++r) {
      float mx = fmaxf(fmaxf(sacc[0][r], sacc[1][r]), fmaxf(sacc[2][r], sacc[3][r]));
      #pragma unroll
      for (int off = 1; off < 16; off <<= 1) mx = fmaxf(mx, __shfl_xor(mx, off));
      mnew[r] = fmaxf(m_i[r], mx);
      alpha[r] = __expf(m_i[r] - mnew[r]);
      m_i[r] = mnew[r];
      psum[r] = 0.f;
    }
    #pragma unroll
    for (int ni = 0; ni < 4; ++ni) {
      #pragma unroll
      for (int r = 0; r < 4; ++r) {
        float p = __expf(sacc[ni][r] - mnew[r]);
        psum[r] += p;
        Ps[w][(quad * 4 + r) * 72 + ni * 16 + l15] = f2bf(p);
      }
    }
    #pragma unroll
    for (int r = 0; r < 4; ++r) {
      float ps = psum[r];
      #pragma unroll
      for (int off = 1; off < 16; off <<= 1) ps += __shfl_xor(ps, off);
      l_i[r] = l_i[r] * alpha[r] + ps;
    }

    bf16x8 pfrag[2];
    #pragma unroll
    for (int c = 0; c < 2; ++c)
      pfrag[c] = *(const bf16x8*)&Ps[w][l15 * 72 + c * 32 + quad * 8];

    #pragma unroll
    for (int ni = 0; ni < 4; ++ni)
      #pragma unroll
      for (int r = 0; r < 4; ++r) oacc[ni][r] *= alpha[r];
    #pragma unroll
    for (int c = 0; c < 2; ++c) {
      #pragma unroll
      for (int ni = 0; ni < 4; ++ni) {
        bf16x8 vf = *(const bf16x8*)&Vt[(ni * 16 + l15) * 72 + c * 32 + quad * 8];
        oacc[ni] = __builtin_amdgcn_mfma_f32_16x16x32_bf16(pfrag[c], vf, oacc[ni], 0, 0, 0);
      }
    }
  }

  #pragma unroll
  for (int ni = 0; ni < 4; ++ni) {
    #pragma unroll
    for (int r = 0; r < 4; ++r) {
      int t = tg0 + r;
      int d = ni * 16 + l15;
      Ob[(size_t)t * 1024 + d] = f2bf(oacc[ni][r] / l_i[r]);
    }
  }
}

extern "C" void kernel_launch(void* const* d_in, const int* in_sizes, int n_in,
                              void* d_out, int out_size, void* d_ws, size_t ws_size,
                              hipStream_t stream) {
  const void* x_in   = d_in[0];
  const void* enc_in = d_in[1];
  const void* ln1_w = d_in[4];  const void* ln1_b = d_in[5];
  const void* qkv_w = d_in[6];  const void* qkv_b = d_in[7];
  const void* proj_w = d_in[8]; const void* proj_b = d_in[9];
  const void* ln2_w = d_in[10]; const void* ln2_b = d_in[11];
  const void* q_w = d_in[12];   const void* q_b = d_in[13];
  const void* k_w = d_in[14];   const void* k_b = d_in[15];
  const void* v_w = d_in[16];   const void* v_b = d_in[17];
  const void* out_w = d_in[18]; const void* out_b = d_in[19];
  const void* ln3_w = d_in[20]; const void* ln3_b = d_in[21];
  const void* mlp1_w = d_in[22]; const void* mlp1_b = d_in[23];
  const void* mlp2_w = d_in[24]; const void* mlp2_b = d_in[25];

  char* ws = (char*)d_ws;
  size_t off = 0;
  auto alloc = [&](size_t bytes) { char* p = ws + off; off += (bytes + 255) & ~(size_t)255; return p; };
  float* xf   = (float*)alloc(4096ull * 1024 * 4);
  u16* hb     = (u16*)alloc(4096ull * 1024 * 2);
  u16* big    = (u16*)alloc(4096ull * 4096 * 2);
  u16* wT     = (u16*)alloc(3072ull * 1024 * 2);
  u16* encb   = (u16*)alloc(2304ull * 768 * 2);
  u16* pool   = (u16*)alloc(20480ull * 2);
  int* flag   = (int*)alloc(256);
  (void)ws_size;

  u16* q_bf = big;
  u16* k_bf = big + 4096ull * 1024;
  u16* v_bf = big + (4096ull + 2304) * 1024;

  u16 *p_ln1w = pool, *p_ln1b = pool + 1024, *p_ln2w = pool + 2048, *p_ln2b = pool + 3072;
  u16 *p_ln3w = pool + 4096, *p_ln3b = pool + 5120;
  u16 *p_qkvb = pool + 6144, *p_projb = pool + 9216, *p_qb = pool + 10240, *p_kb = pool + 11264;
  u16 *p_vb = pool + 12288, *p_outb = pool + 13312, *p_m1b = pool + 14336, *p_m2b = pool + 18432;

  // ---- dtype sniff + input conversion ----
  sniff_kernel<<<1, 64, 0, stream>>>((const u16*)x_in, flag);
  in2f32_kernel<<<4096, 256, 0, stream>>>(x_in, xf, 1048576, flag);
  in2bf_kernel<<<1728, 256, 0, stream>>>(enc_in, encb, 442368, flag);
  in2bf_kernel<<<1, 256, 0, stream>>>(ln1_w, p_ln1w, 256, flag);
  in2bf_kernel<<<1, 256, 0, stream>>>(ln1_b, p_ln1b, 256, flag);
  in2bf_kernel<<<1, 256, 0, stream>>>(ln2_w, p_ln2w, 256, flag);
  in2bf_kernel<<<1, 256, 0, stream>>>(ln2_b, p_ln2b, 256, flag);
  in2bf_kernel<<<1, 256, 0, stream>>>(ln3_w, p_ln3w, 256, flag);
  in2bf_kernel<<<1, 256, 0, stream>>>(ln3_b, p_ln3b, 256, flag);
  in2bf_kernel<<<3, 256, 0, stream>>>(qkv_b, p_qkvb, 768, flag);
  in2bf_kernel<<<1, 256, 0, stream>>>(proj_b, p_projb, 256, flag);
  in2bf_kernel<<<1, 256, 0, stream>>>(q_b, p_qb, 256, flag);
  in2bf_kernel<<<1, 256, 0, stream>>>(k_b, p_kb, 256, flag);
  in2bf_kernel<<<1, 256, 0, stream>>>(v_b, p_vb, 256, flag);
  in2bf_kernel<<<1, 256, 0, stream>>>(out_b, p_outb, 256, flag);
  in2bf_kernel<<<4, 256, 0, stream>>>(mlp1_b, p_m1b, 1024, flag);
  in2bf_kernel<<<1, 256, 0, stream>>>(mlp2_b, p_m2b, 256, flag);

  // ---- self-attention block ----
  ln_kernel<<<4096, 256, 0, stream>>>(xf, p_ln1w, p_ln1b, hb);
  transpose_k<<<dim3(96, 32), 256, 0, stream>>>(qkv_w, wT, 1024, 3072, flag);
  gemm_tn<0><<<dim3(24, 32), 256, 0, stream>>>(hb, wT, p_qkvb, nullptr, nullptr, big, 4096, 3072, 1024, flag);
  attn_mfma<<<dim3(16, 64), 256, 0, stream>>>(big, big + 1024, big + 2048, hb, 1024, 1024, 3072, 3072, 1);
  transpose_k<<<dim3(32, 32), 256, 0, stream>>>(proj_w, wT, 1024, 1024, flag);
  gemm_tn<1><<<dim3(8, 32), 256, 0, stream>>>(hb, wT, p_projb, xf, xf, nullptr, 4096, 1024, 1024, flag);

  // ---- cross-attention block ----
  ln_kernel<<<4096, 256, 0, stream>>>(xf, p_ln2w, p_ln2b, hb);
  transpose_k<<<dim3(32, 32), 256, 0, stream>>>(q_w, wT, 1024, 1024, flag);
  gemm_tn<0><<<dim3(8, 32), 256, 0, stream>>>(hb, wT, p_qb, nullptr, nullptr, q_bf, 4096, 1024, 1024, flag);
  transpose_k<<<dim3(32, 24), 256, 0, stream>>>(k_w, wT, 768, 1024, flag);
  gemm_tn<0><<<dim3(8, 18), 256, 0, stream>>>(encb, wT, p_kb, nullptr, nullptr, k_bf, 2304, 1024, 768, flag);
  transpose_k<<<dim3(32, 24), 256, 0, stream>>>(v_w, wT, 768, 1024, flag);
  gemm_tn<0><<<dim3(8, 18), 256, 0, stream>>>(encb, wT, p_vb, nullptr, nullptr, v_bf, 2304, 1024, 768, flag);
  attn_mfma<<<dim3(16, 64), 256, 0, stream>>>(q_bf, k_bf, v_bf, hb, 1024, 576, 1024, 1024, 0);
  transpose_k<<<dim3(32, 32), 256, 0, stream>>>(out_w, wT, 1024, 1024, flag);
  gemm_tn<1><<<dim3(8, 32), 256, 0, stream>>>(hb, wT, p_outb, xf, xf, nullptr, 4096, 1024, 1024, flag);

  // ---- MLP block ----
  ln_kernel<<<4096, 256, 0, stream>>>(xf, p_ln3w, p_ln3b, hb);
  transpose_k<<<dim3(128, 32), 256, 0, stream>>>(mlp1_w, wT, 1024, 4096, flag);
  gemm_tn<2><<<dim3(32, 32), 256, 0, stream>>>(hb, wT, p_m1b, nullptr, nullptr, big, 4096, 4096, 1024, flag);
  transpose_k<<<dim3(32, 128), 256, 0, stream>>>(mlp2_w, wT, 4096, 1024, flag);
  gemm_tn<3><<<dim3(8, 32), 256, 0, stream>>>(big, wT, p_m2b, xf, nullptr, d_out, 4096, 1024, 4096, flag);
}

// Round 7
// 642.487 us; speedup vs baseline: 5.0028x; 1.0180x over previous
//
#include <hip/hip_runtime.h>
#include <hip/hip_bf16.h>

typedef unsigned short u16;
typedef __bf16 bf16x8 __attribute__((ext_vector_type(8)));
typedef float f32x4 __attribute__((ext_vector_type(4)));

__device__ __forceinline__ float bf2f(u16 v) { return __uint_as_float(((unsigned)v) << 16); }
__device__ __forceinline__ u16 f2bf(float f) {
  unsigned u = __float_as_uint(f);
  u += 0x7FFFu + ((u >> 16) & 1u);
  return (u16)(u >> 16);
}
__device__ __forceinline__ float gelu_exact(float x) {
  return 0.5f * x * (1.0f + erff(x * 0.70710678118654752f));
}

// async global->LDS DMA, 16B per lane; LDS dest = wave-uniform base + lane*16
__device__ __forceinline__ void async_load16(const u16* g, u16* l) {
  __builtin_amdgcn_global_load_lds((const __attribute__((address_space(1))) void*)g,
                                   (__attribute__((address_space(3))) void*)l, 16, 0, 0);
}

// ---------------- dtype sniffer (1 = bf16, 0 = fp32) ----------------
__global__ void sniff_kernel(const u16* __restrict__ x, int* __restrict__ flag) {
  int tid = threadIdx.x;  // 64
  int hits = 0;
  #pragma unroll
  for (int s = 0; s < 2; ++s) {
    float f = fabsf(bf2f(x[2 * (tid + 64 * s)]));
    hits += (f >= 0.00390625f && f <= 16.0f) ? 1 : 0;
  }
  #pragma unroll
  for (int off = 32; off; off >>= 1) hits += __shfl_xor(hits, off);
  if (tid == 0) flag[0] = (hits >= 64) ? 1 : 0;
}

// ---------------- input -> bf16 copy/convert ----------------
__global__ __launch_bounds__(256) void in2bf_kernel(const void* __restrict__ src, u16* __restrict__ dst,
                                                    int n4, const int* __restrict__ flagp) {
  int i = blockIdx.x * 256 + threadIdx.x;
  if (i >= n4) return;
  if (*flagp) {
    ((ushort4*)dst)[i] = ((const ushort4*)src)[i];
  } else {
    float4 v = ((const float4*)src)[i];
    ushort4 o; o.x = f2bf(v.x); o.y = f2bf(v.y); o.z = f2bf(v.z); o.w = f2bf(v.w);
    ((ushort4*)dst)[i] = o;
  }
}

// ---------------- input -> fp32 copy/convert (residual stream init) ----------------
__global__ __launch_bounds__(256) void in2f32_kernel(const void* __restrict__ src, float* __restrict__ dst,
                                                     int n4, const int* __restrict__ flagp) {
  int i = blockIdx.x * 256 + threadIdx.x;
  if (i >= n4) return;
  if (*flagp) {
    ushort4 v = ((const ushort4*)src)[i];
    float4 o; o.x = bf2f(v.x); o.y = bf2f(v.y); o.z = bf2f(v.z); o.w = bf2f(v.w);
    ((float4*)dst)[i] = o;
  } else {
    ((float4*)dst)[i] = ((const float4*)src)[i];
  }
}

// ---------------- weight transpose: in [R,C] -> out [C,R] bf16, dual-dtype read ----------------
__global__ __launch_bounds__(256) void transpose_k(const void* __restrict__ in_, u16* __restrict__ out,
                                                   int R, int C, const int* __restrict__ flagp) {
  int flag = *flagp;
  __shared__ u16 tile[32][33];
  int c0 = blockIdx.x * 32, r0 = blockIdx.y * 32;
  int tx = threadIdx.x & 31, ty = threadIdx.x >> 5;
  #pragma unroll
  for (int j = 0; j < 32; j += 8) {
    size_t idx = (size_t)(r0 + ty + j) * C + c0 + tx;
    tile[ty + j][tx] = flag ? ((const u16*)in_)[idx] : f2bf(((const float*)in_)[idx]);
  }
  __syncthreads();
  #pragma unroll
  for (int j = 0; j < 32; j += 8)
    out[(size_t)(c0 + ty + j) * R + r0 + tx] = tile[tx][ty + j];
}

// ---------------- LayerNorm: fp32 in -> bf16 out, D=1024 ----------------
__global__ __launch_bounds__(256) void ln_kernel(const float* __restrict__ x,
                                                 const u16* __restrict__ w, const u16* __restrict__ b,
                                                 u16* __restrict__ out) {
  int row = blockIdx.x, tid = threadIdx.x;
  float4 v = ((const float4*)(x + (size_t)row * 1024))[tid];
  float s = v.x + v.y + v.z + v.w;
  #pragma unroll
  for (int off = 32; off; off >>= 1) s += __shfl_xor(s, off);
  __shared__ float red1[4], red2[4];
  if ((tid & 63) == 0) red1[tid >> 6] = s;
  __syncthreads();
  float mean = (red1[0] + red1[1] + red1[2] + red1[3]) * (1.0f / 1024.0f);
  float d0 = v.x - mean, d1 = v.y - mean, d2 = v.z - mean, d3 = v.w - mean;
  float vs = d0 * d0 + d1 * d1 + d2 * d2 + d3 * d3;
  #pragma unroll
  for (int off = 32; off; off >>= 1) vs += __shfl_xor(vs, off);
  if ((tid & 63) == 0) red2[tid >> 6] = vs;
  __syncthreads();
  float var = (red2[0] + red2[1] + red2[2] + red2[3]) * (1.0f / 1024.0f);
  float rs = rsqrtf(var + 1e-5f);
  int c = tid * 4;
  ushort4 o;
  o.x = f2bf(d0 * rs * bf2f(w[c + 0]) + bf2f(b[c + 0]));
  o.y = f2bf(d1 * rs * bf2f(w[c + 1]) + bf2f(b[c + 1]));
  o.z = f2bf(d2 * rs * bf2f(w[c + 2]) + bf2f(b[c + 2]));
  o.w = f2bf(d3 * rs * bf2f(w[c + 3]) + bf2f(b[c + 3]));
  ((ushort4*)(out + (size_t)row * 1024))[tid] = o;
}

// ---------------- TN GEMM: C[M,N] = A[M,K] @ Bt[N,K]^T + bias, bf16 MFMA ----------------
// Staging via global_load_lds (16B/lane DMA), XOR-swizzled k-blocks (2-way banks, free).
// NB=2: double-buffered DMA (for 1-block/CU grids: hides DMA latency under compute —
//       the barrier's vmcnt(0) drain then waits on a DMA issued one compute-phase ago).
// NB=1: single buffer (for >=3-blocks/CU grids where implicit wave overlap suffices
//       and 64 KB LDS would cut occupancy — m132 mechanism).
template <int MODE, int NB>
__global__ __launch_bounds__(256) void gemm_tn(const u16* __restrict__ A, const u16* __restrict__ Bt,
                                               const u16* __restrict__ bias,
                                               const float* __restrict__ resid_in, float* __restrict__ resid_out,
                                               void* __restrict__ outp, int M, int N, int K,
                                               const int* __restrict__ flagp) {
  __shared__ __align__(16) u16 As[NB][128 * 64];
  __shared__ __align__(16) u16 Bs[NB][128 * 64];
  int n0 = blockIdx.x * 128, m0 = blockIdx.y * 128;
  int tid = threadIdx.x;
  int lane = tid & 63, w = tid >> 6;
  int wm = w & 1, wn = w >> 1;
  int quad = lane >> 4, l15 = lane & 15;
  int sw = l15 & 7;
  int flag = (MODE == 3) ? *flagp : 0;
  f32x4 acc[4][4];
  #pragma unroll
  for (int i = 0; i < 4; i++)
    #pragma unroll
    for (int j = 0; j < 4; j++) acc[i][j] = (f32x4){0.f, 0.f, 0.f, 0.f};

  // staging geometry: lane covers row (lane>>3) of an 8-row group, swizzled k-block
  int srow8 = lane >> 3;
  int scol = ((lane & 7) ^ srow8) * 8;
  const u16* Abase = A + (size_t)(m0 + srow8) * K + scol;
  const u16* Bbase = Bt + (size_t)(n0 + srow8) * K + scol;

  auto issue = [&](int k0, int buf) {
    #pragma unroll
    for (int j = 0; j < 4; ++j) {
      int r0 = (w * 4 + j) * 8;
      async_load16(Abase + (size_t)r0 * K + k0, &As[buf][r0 * 64]);
      async_load16(Bbase + (size_t)r0 * K + k0, &Bs[buf][r0 * 64]);
    }
  };

  auto compute = [&](int buf) {
    #pragma unroll
    for (int kk = 0; kk < 64; kk += 32) {
      int cbase = (kk >> 3) + quad;
      int slot = (cbase ^ sw) << 3;
      bf16x8 af[4], bfr[4];
      #pragma unroll
      for (int i = 0; i < 4; i++) {
        af[i]  = *(const bf16x8*)&As[buf][(wm * 64 + i * 16 + l15) * 64 + slot];
        bfr[i] = *(const bf16x8*)&Bs[buf][(wn * 64 + i * 16 + l15) * 64 + slot];
      }
      #pragma unroll
      for (int mi = 0; mi < 4; mi++)
        #pragma unroll
        for (int ni = 0; ni < 4; ni++)
          acc[mi][ni] = __builtin_amdgcn_mfma_f32_16x16x32_bf16(af[mi], bfr[ni], acc[mi][ni], 0, 0, 0);
    }
  };

  if (NB == 2) {
    issue(0, 0);
    int cur = 0;
    for (int k0 = 0; k0 < K; k0 += 64) {
      __syncthreads();                 // drains DMA for tile k0 (issued one phase ago)
      if (k0 + 64 < K) issue(k0 + 64, cur ^ 1);
      compute(cur);
      cur ^= 1;
    }
  } else {
    for (int k0 = 0; k0 < K; k0 += 64) {
      issue(k0, 0);
      __syncthreads();
      compute(0);
      __syncthreads();
    }
  }

  int col_base = n0 + wn * 64, row_base = m0 + wm * 64;
  #pragma unroll
  for (int mi = 0; mi < 4; mi++) {
    #pragma unroll
    for (int ni = 0; ni < 4; ni++) {
      int col = col_base + ni * 16 + l15;
      float bv = bf2f(bias[col]);
      #pragma unroll
      for (int r = 0; r < 4; r++) {
        int row = row_base + mi * 16 + quad * 4 + r;
        float vv = acc[mi][ni][r] + bv;
        size_t idx = (size_t)row * N + col;
        if (MODE == 0) ((u16*)outp)[idx] = f2bf(vv);
        else if (MODE == 1) resid_out[idx] = resid_in[idx] + vv;
        else if (MODE == 2) ((u16*)outp)[idx] = f2bf(gelu_exact(vv));
        else {
          float ov = resid_in[idx] + vv;
          if (flag) ((u16*)outp)[idx] = f2bf(ov);
          else ((float*)outp)[idx] = ov;
        }
      }
    }
  }
}

// ---------------- MFMA flash attention, HD=64 ----------------
__global__ __launch_bounds__(256) void attn_mfma(const u16* __restrict__ Q, const u16* __restrict__ K,
                                                 const u16* __restrict__ V, u16* __restrict__ O,
                                                 int T, int S, int qstride, int kstride, int causal) {
  int bh = blockIdx.y, b = bh >> 4, h = bh & 15;
  const u16* Qb = Q + (size_t)b * T * qstride + h * 64;
  const u16* Kb = K + (size_t)b * S * kstride + h * 64;
  const u16* Vb = V + (size_t)b * S * kstride + h * 64;
  u16* Ob = O + (size_t)b * T * 1024 + h * 64;

  int tid = threadIdx.x, lane = tid & 63, w = tid >> 6;
  int quad = lane >> 4, l15 = lane & 15;
  int qt = blockIdx.x * 64;

  __shared__ __align__(16) u16 Ks[64 * 72];
  __shared__ __align__(16) u16 Vt[64 * 72];
  __shared__ __align__(16) u16 Ps[4][16 * 72];

  int sr = tid >> 2, sc0 = (tid & 3) * 16;

  *(uint4*)&Ks[sr * 72 + sc0]     = *(const uint4*)&Qb[(size_t)(qt + sr) * qstride + sc0];
  *(uint4*)&Ks[sr * 72 + sc0 + 8] = *(const uint4*)&Qb[(size_t)(qt + sr) * qstride + sc0 + 8];
  __syncthreads();
  bf16x8 qfrag[2];
  #pragma unroll
  for (int c = 0; c < 2; ++c)
    qfrag[c] = *(const bf16x8*)&Ks[(w * 16 + l15) * 72 + c * 32 + quad * 8];

  float m_i[4], l_i[4];
  f32x4 oacc[4];
  #pragma unroll
  for (int r = 0; r < 4; ++r) { m_i[r] = -1e30f; l_i[r] = 0.f; }
  #pragma unroll
  for (int ni = 0; ni < 4; ++ni) oacc[ni] = (f32x4){0.f, 0.f, 0.f, 0.f};

  int nk = causal ? (blockIdx.x + 1) * 64 : S;
  int tg0 = qt + w * 16 + quad * 4;

  for (int s0 = 0; s0 < nk; s0 += 64) {
    __syncthreads();
    *(uint4*)&Ks[sr * 72 + sc0]     = *(const uint4*)&Kb[(size_t)(s0 + sr) * kstride + sc0];
    *(uint4*)&Ks[sr * 72 + sc0 + 8] = *(const uint4*)&Kb[(size_t)(s0 + sr) * kstride + sc0 + 8];
    uint4 v0 = *(const uint4*)&Vb[(size_t)(s0 + sr) * kstride + sc0];
    uint4 v1 = *(const uint4*)&Vb[(size_t)(s0 + sr) * kstride + sc0 + 8];
    union { uint4 u[2]; u16 e[16]; } vv; vv.u[0] = v0; vv.u[1] = v1;
    #pragma unroll
    for (int j = 0; j < 16; ++j) Vt[(sc0 + j) * 72 + sr] = vv.e[j];
    __syncthreads();

    f32x4 sacc[4];
    #pragma unroll
    for (int ni = 0; ni < 4; ++ni) sacc[ni] = (f32x4){0.f, 0.f, 0.f, 0.f};
    #pragma unroll
    for (int c = 0; c < 2; ++c) {
      #pragma unroll
      for (int ni = 0; ni < 4; ++ni) {
        bf16x8 kf = *(const bf16x8*)&Ks[(ni * 16 + l15) * 72 + c * 32 + quad * 8];
        sacc[ni] = __builtin_amdgcn_mfma_f32_16x16x32_bf16(qfrag[c], kf, sacc[ni], 0, 0, 0);
      }
    }

    #pragma unroll
    for (int ni = 0; ni < 4; ++ni) {
      int key = s0 + ni * 16 + l15;
      #pragma unroll
      for (int r = 0; r < 4; ++r) {
        float sv = sacc[ni][r] * 0.125f;
        if (causal && key > tg0 + r) sv = -1e30f;
        sacc[ni][r] = sv;
      }
    }

    float mnew[4], alpha[4], psum[4];
    #pragma unroll
    for (int r = 0; r < 4; ++r) {
      float mx = fmaxf(fmaxf(sacc[0][r], sacc[1][r]), fmaxf(sacc[2][r], sacc[3][r]));
      #pragma unroll
      for (int off = 1; off < 16; off <<= 1) mx = fmaxf(mx, __shfl_xor(mx, off));
      mnew[r] = fmaxf(m_i[r], mx);
      alpha[r] = __expf(m_i[r] - mnew[r]);
      m_i[r] = mnew[r];
      psum[r] = 0.f;
    }
    #pragma unroll
    for (int ni = 0; ni < 4; ++ni) {
      #pragma unroll
      for (int r = 0; r < 4; ++r) {
        float p = __expf(sacc[ni][r] - mnew[r]);
        psum[r] += p;
        Ps[w][(quad * 4 + r) * 72 + ni * 16 + l15] = f2bf(p);
      }
    }
    #pragma unroll
    for (int r = 0; r < 4; ++r) {
      float ps = psum[r];
      #pragma unroll
      for (int off = 1; off < 16; off <<= 1) ps += __shfl_xor(ps, off);
      l_i[r] = l_i[r] * alpha[r] + ps;
    }

    bf16x8 pfrag[2];
    #pragma unroll
    for (int c = 0; c < 2; ++c)
      pfrag[c] = *(const bf16x8*)&Ps[w][l15 * 72 + c * 32 + quad * 8];

    #pragma unroll
    for (int ni = 0; ni < 4; ++ni)
      #pragma unroll
      for (int r = 0; r < 4; ++r) oacc[ni][r] *= alpha[r];
    #pragma unroll
    for (int c = 0; c < 2; ++c) {
      #pragma unroll
      for (int ni = 0; ni < 4; ++ni) {
        bf16x8 vf = *(const bf16x8*)&Vt[(ni * 16 + l15) * 72 + c * 32 + quad * 8];
        oacc[ni] = __builtin_amdgcn_mfma_f32_16x16x32_bf16(pfrag[c], vf, oacc[ni], 0, 0, 0);
      }
    }
  }

  #pragma unroll
  for (int ni = 0; ni < 4; ++ni) {
    #pragma unroll
    for (int r = 0; r < 4; ++r) {
      int t = tg0 + r;
      int d = ni * 16 + l15;
      Ob[(size_t)t * 1024 + d] = f2bf(oacc[ni][r] / l_i[r]);
    }
  }
}

extern "C" void kernel_launch(void* const* d_in, const int* in_sizes, int n_in,
                              void* d_out, int out_size, void* d_ws, size_t ws_size,
                              hipStream_t stream) {
  const void* x_in   = d_in[0];
  const void* enc_in = d_in[1];
  const void* ln1_w = d_in[4];  const void* ln1_b = d_in[5];
  const void* qkv_w = d_in[6];  const void* qkv_b = d_in[7];
  const void* proj_w = d_in[8]; const void* proj_b = d_in[9];
  const void* ln2_w = d_in[10]; const void* ln2_b = d_in[11];
  const void* q_w = d_in[12];   const void* q_b = d_in[13];
  const void* k_w = d_in[14];   const void* k_b = d_in[15];
  const void* v_w = d_in[16];   const void* v_b = d_in[17];
  const void* out_w = d_in[18]; const void* out_b = d_in[19];
  const void* ln3_w = d_in[20]; const void* ln3_b = d_in[21];
  const void* mlp1_w = d_in[22]; const void* mlp1_b = d_in[23];
  const void* mlp2_w = d_in[24]; const void* mlp2_b = d_in[25];

  char* ws = (char*)d_ws;
  size_t off = 0;
  auto alloc = [&](size_t bytes) { char* p = ws + off; off += (bytes + 255) & ~(size_t)255; return p; };
  float* xf   = (float*)alloc(4096ull * 1024 * 4);
  u16* hb     = (u16*)alloc(4096ull * 1024 * 2);
  u16* big    = (u16*)alloc(4096ull * 4096 * 2);
  u16* wT     = (u16*)alloc(3072ull * 1024 * 2);
  u16* encb   = (u16*)alloc(2304ull * 768 * 2);
  u16* pool   = (u16*)alloc(20480ull * 2);
  int* flag   = (int*)alloc(256);
  (void)ws_size;

  u16* q_bf = big;
  u16* k_bf = big + 4096ull * 1024;
  u16* v_bf = big + (4096ull + 2304) * 1024;

  u16 *p_ln1w = pool, *p_ln1b = pool + 1024, *p_ln2w = pool + 2048, *p_ln2b = pool + 3072;
  u16 *p_ln3w = pool + 4096, *p_ln3b = pool + 5120;
  u16 *p_qkvb = pool + 6144, *p_projb = pool + 9216, *p_qb = pool + 10240, *p_kb = pool + 11264;
  u16 *p_vb = pool + 12288, *p_outb = pool + 13312, *p_m1b = pool + 14336, *p_m2b = pool + 18432;

  // ---- dtype sniff + input conversion ----
  sniff_kernel<<<1, 64, 0, stream>>>((const u16*)x_in, flag);
  in2f32_kernel<<<4096, 256, 0, stream>>>(x_in, xf, 1048576, flag);
  in2bf_kernel<<<1728, 256, 0, stream>>>(enc_in, encb, 442368, flag);
  in2bf_kernel<<<1, 256, 0, stream>>>(ln1_w, p_ln1w, 256, flag);
  in2bf_kernel<<<1, 256, 0, stream>>>(ln1_b, p_ln1b, 256, flag);
  in2bf_kernel<<<1, 256, 0, stream>>>(ln2_w, p_ln2w, 256, flag);
  in2bf_kernel<<<1, 256, 0, stream>>>(ln2_b, p_ln2b, 256, flag);
  in2bf_kernel<<<1, 256, 0, stream>>>(ln3_w, p_ln3w, 256, flag);
  in2bf_kernel<<<1, 256, 0, stream>>>(ln3_b, p_ln3b, 256, flag);
  in2bf_kernel<<<3, 256, 0, stream>>>(qkv_b, p_qkvb, 768, flag);
  in2bf_kernel<<<1, 256, 0, stream>>>(proj_b, p_projb, 256, flag);
  in2bf_kernel<<<1, 256, 0, stream>>>(q_b, p_qb, 256, flag);
  in2bf_kernel<<<1, 256, 0, stream>>>(k_b, p_kb, 256, flag);
  in2bf_kernel<<<1, 256, 0, stream>>>(v_b, p_vb, 256, flag);
  in2bf_kernel<<<1, 256, 0, stream>>>(out_b, p_outb, 256, flag);
  in2bf_kernel<<<4, 256, 0, stream>>>(mlp1_b, p_m1b, 1024, flag);
  in2bf_kernel<<<1, 256, 0, stream>>>(mlp2_b, p_m2b, 256, flag);

  // ---- self-attention block ----
  ln_kernel<<<4096, 256, 0, stream>>>(xf, p_ln1w, p_ln1b, hb);
  transpose_k<<<dim3(96, 32), 256, 0, stream>>>(qkv_w, wT, 1024, 3072, flag);
  gemm_tn<0, 1><<<dim3(24, 32), 256, 0, stream>>>(hb, wT, p_qkvb, nullptr, nullptr, big, 4096, 3072, 1024, flag);
  attn_mfma<<<dim3(16, 64), 256, 0, stream>>>(big, big + 1024, big + 2048, hb, 1024, 1024, 3072, 3072, 1);
  transpose_k<<<dim3(32, 32), 256, 0, stream>>>(proj_w, wT, 1024, 1024, flag);
  gemm_tn<1, 2><<<dim3(8, 32), 256, 0, stream>>>(hb, wT, p_projb, xf, xf, nullptr, 4096, 1024, 1024, flag);

  // ---- cross-attention block ----
  ln_kernel<<<4096, 256, 0, stream>>>(xf, p_ln2w, p_ln2b, hb);
  transpose_k<<<dim3(32, 32), 256, 0, stream>>>(q_w, wT, 1024, 1024, flag);
  gemm_tn<0, 2><<<dim3(8, 32), 256, 0, stream>>>(hb, wT, p_qb, nullptr, nullptr, q_bf, 4096, 1024, 1024, flag);
  transpose_k<<<dim3(32, 24), 256, 0, stream>>>(k_w, wT, 768, 1024, flag);
  gemm_tn<0, 2><<<dim3(8, 18), 256, 0, stream>>>(encb, wT, p_kb, nullptr, nullptr, k_bf, 2304, 1024, 768, flag);
  transpose_k<<<dim3(32, 24), 256, 0, stream>>>(v_w, wT, 768, 1024, flag);
  gemm_tn<0, 2><<<dim3(8, 18), 256, 0, stream>>>(encb, wT, p_vb, nullptr, nullptr, v_bf, 2304, 1024, 768, flag);
  attn_mfma<<<dim3(16, 64), 256, 0, stream>>>(q_bf, k_bf, v_bf, hb, 1024, 576, 1024, 1024, 0);
  transpose_k<<<dim3(32, 32), 256, 0, stream>>>(out_w, wT, 1024, 1024, flag);
  gemm_tn<1, 2><<<dim3(8, 32), 256, 0, stream>>>(hb, wT, p_outb, xf, xf, nullptr, 4096, 1024, 1024, flag);

  // ---- MLP block ----
  ln_kernel<<<4096, 256, 0, stream>>>(xf, p_ln3w, p_ln3b, hb);
  transpose_k<<<dim3(128, 32), 256, 0, stream>>>(mlp1_w, wT, 1024, 4096, flag);
  gemm_tn<2, 1><<<dim3(32, 32), 256, 0, stream>>>(hb, wT, p_m1b, nullptr, nullptr, big, 4096, 4096, 1024, flag);
  transpose_k<<<dim3(32, 128), 256, 0, stream>>>(mlp2_w, wT, 4096, 1024, flag);
  gemm_tn<3, 2><<<dim3(8, 32), 256, 0, stream>>>(big, wT, p_m2b, xf, nullptr, d_out, 4096, 1024, 4096, flag);
}